// Round 7
// baseline (177.919 us; speedup 1.0000x reference)
//
#include <hip/hip_runtime.h>
#include <hip/hip_bf16.h>
#include <math.h>

typedef __bf16 bf16;
typedef __bf16 bf16x8 __attribute__((ext_vector_type(8)));
typedef __bf16 bf16x4 __attribute__((ext_vector_type(4)));
typedef float  f32x4  __attribute__((ext_vector_type(4)));
typedef _Float16 halfx4 __attribute__((ext_vector_type(4)));

#define MFMA(a, b, c) __builtin_amdgcn_mfma_f32_16x16x32_bf16((a), (b), (c), 0, 0, 0)
#define LOG2E 1.4426950408889634f

// ---------------------------------------------------------------------------
// Kernel 0: precast w_qkv^T -> wqT (bf16 [576][192]) and w_proj^T -> wpT
// (bf16 [192][192]).
// ---------------------------------------------------------------------------
__global__ void precast_kernel(const float* __restrict__ w_qkv,
                               const float* __restrict__ w_proj,
                               bf16* __restrict__ wqT, bf16* __restrict__ wpT) {
  int idx = blockIdx.x * 256 + threadIdx.x;
  if (idx < 576 * 192) {
    int c = idx / 192, k = idx % 192;
    wqT[idx] = (bf16)w_qkv[k * 576 + c];
  } else {
    int i2 = idx - 576 * 192;
    if (i2 < 192 * 192) {
      int c = i2 / 192, k = i2 % 192;
      wpT[i2] = (bf16)w_proj[k * 192 + c];
    }
  }
}

// ---------------------------------------------------------------------------
// Kernel A: relative-position-bias MLP (961 rows, 2->12->12->12->6).
// Output pos_out[h][i] (head-major).
// ---------------------------------------------------------------------------
__global__ void pos_mlp_kernel(
    const float* __restrict__ pw0, const float* __restrict__ pb0,
    const float* __restrict__ g1,  const float* __restrict__ be1,
    const float* __restrict__ w1,  const float* __restrict__ b1,
    const float* __restrict__ g2,  const float* __restrict__ be2,
    const float* __restrict__ w2,  const float* __restrict__ b2,
    const float* __restrict__ g3,  const float* __restrict__ be3,
    const float* __restrict__ w3,  const float* __restrict__ b3,
    float* __restrict__ pos_out) {
  int i = blockIdx.x * blockDim.x + threadIdx.x;
  if (i >= 961) return;
  float bh = (float)(i / 31) - 15.0f;
  float bw = (float)(i % 31) - 15.0f;
  float xv[12];
#pragma unroll
  for (int j = 0; j < 12; j++) xv[j] = bh * pw0[j] + bw * pw0[12 + j] + pb0[j];
  const float* G[3]  = {g1, g2, g3};
  const float* BE[3] = {be1, be2, be3};
  const float* W[3]  = {w1, w2, w3};
  const float* BB[3] = {b1, b2, b3};
#pragma unroll
  for (int s = 0; s < 3; s++) {
    float m = 0.f;
#pragma unroll
    for (int j = 0; j < 12; j++) m += xv[j];
    m *= (1.0f / 12.0f);
    float v = 0.f;
#pragma unroll
    for (int j = 0; j < 12; j++) { float d = xv[j] - m; v += d * d; }
    v *= (1.0f / 12.0f);
    float inv = 1.0f / sqrtf(v + 1e-5f);
    float y[12];
#pragma unroll
    for (int j = 0; j < 12; j++) {
      float t = (xv[j] - m) * inv * G[s][j] + BE[s][j];
      y[j] = t > 0.f ? t : 0.f;
    }
    int oc = (s == 2) ? 6 : 12;
    float on[12];
    for (int c = 0; c < oc; c++) {
      float acc = BB[s][c];
#pragma unroll
      for (int j = 0; j < 12; j++) acc += y[j] * W[s][j * oc + c];
      on[c] = acc;
    }
    for (int c = 0; c < 12; c++) xv[c] = (c < oc) ? on[c] : 0.f;
  }
  for (int hh = 0; hh < 6; hh++) pos_out[hh * 961 + i] = xv[hh];
}

// ---------------------------------------------------------------------------
// Kernel A2: combined bias precompute.
// biasc[s][h][n][m] (f16) = (mask[s][n][m] + pos[h][rpi(n,m)]) * log2e
// grid (64 s, 6 h), 256 thr; each thread covers one m-quad across 64 n rows.
// ---------------------------------------------------------------------------
__global__ __launch_bounds__(256) void biasprep_kernel(
    const float* __restrict__ mask, const float* __restrict__ posg,
    _Float16* __restrict__ biasc) {
  __shared__ float posh[961];
  const int s = blockIdx.x, h = blockIdx.y;
  for (int i = threadIdx.x; i < 961; i += 256)
    posh[i] = posg[h * 961 + i] * LOG2E;
  __syncthreads();
  const float* mb = mask + (size_t)s * 65536;
  _Float16* ob = biasc + ((size_t)(s * 6 + h)) * 65536;
  const int m0 = (threadIdx.x & 63) * 4;
  const int nb = threadIdx.x >> 6;
  const int rm = m0 >> 4, cm = m0 & 15;
  for (int n = nb; n < 256; n += 4) {
    f32x4 mv = *(const f32x4*)(mb + n * 256 + m0);
    int base = ((n >> 4) - rm + 15) * 31 + ((n & 15) - cm + 15);
    halfx4 o;
#pragma unroll
    for (int j = 0; j < 4; j++)
      o[j] = (_Float16)fmaf(mv[j], LOG2E, posh[base - j]);
    *(halfx4*)(ob + n * 256 + m0) = o;
  }
}

// ---------------------------------------------------------------------------
// Kernel B: QKV GEMM.  grid 512, 4 waves x 32 rows (BM=128, rt=2).
// W^T staged in LDS one mat at a time.  Q pre-scaled by scale*log2e.
// Q,K swapped-MFMA -> [b][h][n][d]; V normal -> vT[b][h][d][n].
// ---------------------------------------------------------------------------
#define SMEM_G (192 * 200 * 2)

__global__ __launch_bounds__(256) void qkv_gemm_kernel(
    const float* __restrict__ x, const bf16* __restrict__ wqT,
    const float* __restrict__ b_qkv, bf16* __restrict__ qw,
    bf16* __restrict__ kw, bf16* __restrict__ vwT) {
  extern __shared__ char smem[];
  bf16* wt = (bf16*)smem;   // [192 c][200 k]
  const int tid = threadIdx.x;
  const int lane = tid & 63, w = tid >> 6;
  const int cI = lane & 15, gI = lane >> 4;
  const int row0 = blockIdx.x * 128 + w * 32;
  const int b = blockIdx.x >> 1;
  const float QSCALE = 0.17677669529663687f * LOG2E;

  bf16x8 afr[2][6];
#pragma unroll
  for (int rt = 0; rt < 2; rt++) {
#pragma unroll
    for (int kk = 0; kk < 6; kk++) {
      const float* p = x + (size_t)(row0 + rt * 16 + cI) * 192 + kk * 32 + gI * 8;
      float4 f0 = *(const float4*)p;
      float4 f1 = *(const float4*)(p + 4);
      bf16x8 a;
      a[0] = (bf16)f0.x; a[1] = (bf16)f0.y; a[2] = (bf16)f0.z; a[3] = (bf16)f0.w;
      a[4] = (bf16)f1.x; a[5] = (bf16)f1.y; a[6] = (bf16)f1.z; a[7] = (bf16)f1.w;
      afr[rt][kk] = a;
    }
  }

#pragma unroll
  for (int mat = 0; mat < 3; mat++) {
    __syncthreads();
#pragma unroll
    for (int it = 0; it < 18; it++) {
      int idx = it * 256 + tid;
      int c = idx / 24, ch = idx % 24;
      bf16x8 v8 = *(const bf16x8*)(wqT + (size_t)(mat * 192 + c) * 192 + ch * 8);
      *(bf16x8*)(wt + c * 200 + ch * 8) = v8;
    }
    __syncthreads();
#pragma unroll
    for (int ct = 0; ct < 12; ct++) {
      bf16x8 wfr[6];
#pragma unroll
      for (int kk = 0; kk < 6; kk++)
        wfr[kk] = *(const bf16x8*)(wt + (ct * 16 + cI) * 200 + kk * 32 + gI * 8);
      if (mat < 2) {
        f32x4 bv4 = *(const f32x4*)(b_qkv + mat * 192 + ct * 16 + gI * 4);
        bf16* dst = (mat == 0) ? qw : kw;
#pragma unroll
        for (int rt = 0; rt < 2; rt++) {
          f32x4 acc = {0.f, 0.f, 0.f, 0.f};
#pragma unroll
          for (int kk = 0; kk < 6; kk++) acc = MFMA(wfr[kk], afr[rt][kk], acc);
          int n = (row0 + rt * 16 + cI) & 255;
          int c0 = ct * 16 + gI * 4;
          int h = c0 >> 5, d0 = c0 & 31;
          bf16x4 o4;
          if (mat == 0) {
#pragma unroll
            for (int r = 0; r < 4; r++) o4[r] = (bf16)((acc[r] + bv4[r]) * QSCALE);
          } else {
#pragma unroll
            for (int r = 0; r < 4; r++) o4[r] = (bf16)(acc[r] + bv4[r]);
          }
          *(bf16x4*)(dst + ((size_t)(b * 6 + h) * 256 + n) * 32 + d0) = o4;
        }
      } else {
        float bv = b_qkv[384 + ct * 16 + cI];
        int c = ct * 16 + cI, h = c >> 5, d = c & 31;
#pragma unroll
        for (int rt = 0; rt < 2; rt++) {
          f32x4 acc = {0.f, 0.f, 0.f, 0.f};
#pragma unroll
          for (int kk = 0; kk < 6; kk++) acc = MFMA(afr[rt][kk], wfr[kk], acc);
          int n0 = ((row0 + rt * 16) & 255) + gI * 4;
          bf16x4 o4;
#pragma unroll
          for (int r = 0; r < 4; r++) o4[r] = (bf16)(acc[r] + bv);
          *(bf16x4*)(vwT + ((size_t)(b * 6 + h) * 32 + d) * 256 + n0) = o4;
        }
      }
    }
  }
}

// ---------------------------------------------------------------------------
// Kernel C: flash attention.  grid 1536 (b,h), 4 waves x 64 Q rows (rt=4).
// Swapped QK^T.  Bias = precomputed f16 (mask+pos)*log2e, direct global load.
// l-sum via ones-MFMA.  Defer-max THR=8.  No block-level staging/syncs.
// LDS: pw 4 x [64][72] bf16 = 36864 B -> 4 blocks/CU.
// ---------------------------------------------------------------------------
#define SMEM_A  (4 * 64 * 72 * 2)

__global__ __launch_bounds__(256, 4) void attn_kernel(
    const bf16* __restrict__ qw, const bf16* __restrict__ kw,
    const bf16* __restrict__ vwT, const _Float16* __restrict__ biasc,
    bf16* __restrict__ ctx) {
  extern __shared__ char smem[];

  const int tid = threadIdx.x;
  const int bid = blockIdx.x;
  const int s_ = bid & 63, j_ = bid >> 6;          // mask slice; XCD = s%8
  const int g_ = j_ & 3, h = j_ >> 2;
  const int b = g_ * 64 + s_;

  const bf16* qb = qw  + (size_t)(b * 6 + h) * 8192;
  const bf16* kb = kw  + (size_t)(b * 6 + h) * 8192;
  const bf16* vb = vwT + (size_t)(b * 6 + h) * 8192;
  const _Float16* bb = biasc + ((size_t)(s_ * 6 + h)) * 65536;

  const int lane = tid & 63, w = tid >> 6;
  const int cI = lane & 15, gI = lane >> 4;
  const int qrow0 = w * 64;
  bf16* pw = (bf16*)(smem + w * 9216);             // per-wave [64][72]

  bf16x8 qfr[4];
#pragma unroll
  for (int rt = 0; rt < 4; rt++)
    qfr[rt] = *(const bf16x8*)(qb + (qrow0 + rt * 16 + cI) * 32 + gI * 8);

  bf16x8 ones8;
#pragma unroll
  for (int j = 0; j < 8; j++) ones8[j] = (bf16)1.0f;

  f32x4 o[4][2];
  f32x4 ol[4];
  float mr[4];
#pragma unroll
  for (int rt = 0; rt < 4; rt++) {
    o[rt][0] = (f32x4){0.f, 0.f, 0.f, 0.f};
    o[rt][1] = (f32x4){0.f, 0.f, 0.f, 0.f};
    ol[rt]   = (f32x4){0.f, 0.f, 0.f, 0.f};
    mr[rt] = -3.0e38f;
  }

  for (int kt = 0; kt < 4; kt++) {
    bf16x8 kfr[4];
#pragma unroll
    for (int ct = 0; ct < 4; ct++)
      kfr[ct] = *(const bf16x8*)(kb + (kt * 64 + ct * 16 + cI) * 32 + gI * 8);
#pragma unroll
    for (int rt = 0; rt < 4; rt++) {
      // bias loads issued before the MFMA cluster (independent)
      const _Float16* brt = bb + (size_t)(qrow0 + rt * 16 + cI) * 256 +
                            kt * 64 + gI * 4;
      halfx4 bv[4];
#pragma unroll
      for (int ct = 0; ct < 4; ct++) bv[ct] = *(const halfx4*)(brt + ct * 16);
      f32x4 sa[4];
      __builtin_amdgcn_s_setprio(1);
#pragma unroll
      for (int ct = 0; ct < 4; ct++) {
        f32x4 z = {0.f, 0.f, 0.f, 0.f};
        sa[ct] = MFMA(kfr[ct], qfr[rt], z);        // swapped: m@row-slot, n@cI
      }
      __builtin_amdgcn_s_setprio(0);
#pragma unroll
      for (int ct = 0; ct < 4; ct++)
#pragma unroll
        for (int r = 0; r < 4; r++) sa[ct][r] += (float)bv[ct][r];
      // row max (n = cI): in-lane 16 + 2 cross-group shuffles
      float t = sa[0][0];
#pragma unroll
      for (int ct = 0; ct < 4; ct++)
#pragma unroll
        for (int r = 0; r < 4; r++) t = fmaxf(t, sa[ct][r]);
      t = fmaxf(t, __shfl_xor(t, 16));
      t = fmaxf(t, __shfl_xor(t, 32));
      // defer-max: only rescale when some row grew by > 8 (in log2 units)
      if (!__all(t - mr[rt] <= 8.0f)) {
        float mn = fmaxf(mr[rt], t);
        float fsc = exp2f(mr[rt] - mn);
        mr[rt] = mn;
        float fr0 = __shfl(fsc, gI * 4 + 0);
        float fr1 = __shfl(fsc, gI * 4 + 1);
        float fr2 = __shfl(fsc, gI * 4 + 2);
        float fr3 = __shfl(fsc, gI * 4 + 3);
        o[rt][0][0] *= fr0; o[rt][1][0] *= fr0; ol[rt][0] *= fr0;
        o[rt][0][1] *= fr1; o[rt][1][1] *= fr1; ol[rt][1] *= fr1;
        o[rt][0][2] *= fr2; o[rt][1][2] *= fr2; ol[rt][2] *= fr2;
        o[rt][0][3] *= fr3; o[rt][1][3] *= fr3; ol[rt][3] *= fr3;
      }
#pragma unroll
      for (int ct = 0; ct < 4; ct++) {
        bf16x4 p4;
#pragma unroll
        for (int r = 0; r < 4; r++) p4[r] = (bf16)exp2f(sa[ct][r] - mr[rt]);
        *(bf16x4*)(pw + (rt * 16 + cI) * 72 + ct * 16 + gI * 4) = p4;
      }
    }
    // V-frag loads (global, independent of P) issued before the P drain
    bf16x8 vfr[2][2];
#pragma unroll
    for (int kc = 0; kc < 2; kc++)
#pragma unroll
      for (int c2 = 0; c2 < 2; c2++)
        vfr[kc][c2] = *(const bf16x8*)(vb + (c2 * 16 + cI) * 256 +
                                       kt * 64 + kc * 32 + gI * 8);
    // this wave's P writes must land before re-reading as A-frags
    asm volatile("s_waitcnt lgkmcnt(0)" ::: "memory");
    __builtin_amdgcn_sched_barrier(0);
    __builtin_amdgcn_s_setprio(1);
#pragma unroll
    for (int kc = 0; kc < 2; kc++) {
#pragma unroll
      for (int rt = 0; rt < 4; rt++) {
        bf16x8 pfr = *(const bf16x8*)(pw + (rt * 16 + cI) * 72 + kc * 32 + gI * 8);
        o[rt][0] = MFMA(pfr, vfr[kc][0], o[rt][0]);
        o[rt][1] = MFMA(pfr, vfr[kc][1], o[rt][1]);
        ol[rt]   = MFMA(pfr, ones8, ol[rt]);       // row-sums, same layout as o
      }
    }
    __builtin_amdgcn_s_setprio(0);
  }
  // ---- epilogue: l already in row-slot layout -> plain divide ----
#pragma unroll
  for (int rt = 0; rt < 4; rt++) {
    f32x4 linv;
#pragma unroll
    for (int r = 0; r < 4; r++) linv[r] = 1.0f / ol[rt][r];
#pragma unroll
    for (int c2 = 0; c2 < 2; c2++) {
#pragma unroll
      for (int r = 0; r < 4; r++) {
        int n = qrow0 + rt * 16 + gI * 4 + r;
        ctx[((size_t)(b << 8) + n) * 192 + h * 32 + c2 * 16 + cI] =
            (bf16)(o[rt][c2][r] * linv[r]);
      }
    }
  }
}

// ---------------------------------------------------------------------------
// Kernel D: out = ctx @ w_proj + b_proj.  grid 512, rt=2, W^T staged in LDS,
// swapped orientation -> float4 stores.
// ---------------------------------------------------------------------------
#define SMEM_C (192 * 200 * 2)

__global__ __launch_bounds__(256) void proj_kernel(
    const bf16* __restrict__ ctx, const bf16* __restrict__ wpT,
    const float* __restrict__ b_proj, float* __restrict__ out) {
  extern __shared__ char smem[];
  bf16* wt = (bf16*)smem;   // [192 c][200 k]
  const int tid = threadIdx.x;
#pragma unroll
  for (int it = 0; it < 18; it++) {
    int idx = it * 256 + tid;
    int c = idx / 24, ch = idx % 24;
    bf16x8 v8 = *(const bf16x8*)(wpT + (size_t)c * 192 + ch * 8);
    *(bf16x8*)(wt + c * 200 + ch * 8) = v8;
  }
  __syncthreads();
  const int lane = tid & 63, w = tid >> 6;
  const int cI = lane & 15, gI = lane >> 4;
  const int row0 = blockIdx.x * 128 + w * 32;
  bf16x8 afr[2][6];
#pragma unroll
  for (int rt = 0; rt < 2; rt++) {
#pragma unroll
    for (int kk = 0; kk < 6; kk++)
      afr[rt][kk] = *(const bf16x8*)(ctx + (size_t)(row0 + rt * 16 + cI) * 192 +
                                     kk * 32 + gI * 8);
  }
#pragma unroll
  for (int ct = 0; ct < 12; ct++) {
    bf16x8 wfr[6];
#pragma unroll
    for (int kk = 0; kk < 6; kk++)
      wfr[kk] = *(const bf16x8*)(wt + (ct * 16 + cI) * 200 + kk * 32 + gI * 8);
    f32x4 bv4 = *(const f32x4*)(b_proj + ct * 16 + gI * 4);
#pragma unroll
    for (int rt = 0; rt < 2; rt++) {
      f32x4 acc = {0.f, 0.f, 0.f, 0.f};
#pragma unroll
      for (int kk = 0; kk < 6; kk++) acc = MFMA(wfr[kk], afr[rt][kk], acc);
      f32x4 res;
#pragma unroll
      for (int r = 0; r < 4; r++) res[r] = acc[r] + bv4[r];
      *(f32x4*)(out + (size_t)(row0 + rt * 16 + cI) * 192 + ct * 16 + gI * 4) = res;
    }
  }
}

// ---------------------------------------------------------------------------
extern "C" void kernel_launch(void* const* d_in, const int* in_sizes, int n_in,
                              void* d_out, int out_size, void* d_ws, size_t ws_size,
                              hipStream_t stream) {
  (void)in_sizes; (void)n_in; (void)out_size; (void)ws_size;
  const float* x      = (const float*)d_in[0];
  const float* mask   = (const float*)d_in[1];
  const float* w_qkv  = (const float*)d_in[2];
  const float* b_qkv  = (const float*)d_in[3];
  const float* w_proj = (const float*)d_in[4];
  const float* b_proj = (const float*)d_in[5];
  const float* pw0    = (const float*)d_in[6];
  const float* pb0    = (const float*)d_in[7];
  const float* g1     = (const float*)d_in[8];
  const float* be1    = (const float*)d_in[9];
  const float* w1     = (const float*)d_in[10];
  const float* b1     = (const float*)d_in[11];
  const float* g2     = (const float*)d_in[12];
  const float* be2    = (const float*)d_in[13];
  const float* w2     = (const float*)d_in[14];
  const float* b2     = (const float*)d_in[15];
  const float* g3     = (const float*)d_in[16];
  const float* be3    = (const float*)d_in[17];
  const float* w3     = (const float*)d_in[18];
  const float* b3     = (const float*)d_in[19];

  // ws layout (peak ~96.3 MB, unchanged):
  //   posw @ 0         (24576)
  //   wqT  @ 24576     (221184)   bf16 [576][192]
  //   wpT  @ 245760    (73728)    bf16 [192][192]
  //   qw   @ 319488    (25165824) bf16 [b][h][n][32]   (pre-scaled by s*log2e)
  //   kw   @ 25485312  (25165824)
  //   vwT  @ 50651136  (25165824) bf16 [b][h][32][n]
  //   ctx  @ 75816960  (25165824)
  // biasc (f16 [64][6][256][256], 50331648 B) lives in d_out — exactly
  // out_size*4 bytes; proj_kernel fully overwrites d_out afterwards.
  char* ws = (char*)d_ws;
  float* posw = (float*)ws;
  bf16*  wqT  = (bf16*)(ws + 24576);
  bf16*  wpT  = (bf16*)(ws + 245760);
  bf16*  qw   = (bf16*)(ws + 319488);
  bf16*  kw   = (bf16*)(ws + 25485312);
  bf16*  vwT  = (bf16*)(ws + 50651136);
  bf16*  ctx  = (bf16*)(ws + 75816960);
  _Float16* biasc = (_Float16*)d_out;
  float* outp = (float*)d_out;

  hipFuncSetAttribute((const void*)qkv_gemm_kernel,
                      hipFuncAttributeMaxDynamicSharedMemorySize, SMEM_G);
  hipFuncSetAttribute((const void*)proj_kernel,
                      hipFuncAttributeMaxDynamicSharedMemorySize, SMEM_C);

  precast_kernel<<<dim3(576), dim3(256), 0, stream>>>(w_qkv, w_proj, wqT, wpT);
  pos_mlp_kernel<<<dim3(4), dim3(256), 0, stream>>>(
      pw0, pb0, g1, be1, w1, b1, g2, be2, w2, b2, g3, be3, w3, b3, posw);
  qkv_gemm_kernel<<<dim3(512), dim3(256), SMEM_G, stream>>>(
      x, wqT, b_qkv, qw, kw, vwT);
  biasprep_kernel<<<dim3(64, 6), dim3(256), 0, stream>>>(mask, posw, biasc);
  attn_kernel<<<dim3(1536), dim3(256), SMEM_A, stream>>>(
      qw, kw, vwT, biasc, ctx);
  proj_kernel<<<dim3(512), dim3(256), SMEM_C, stream>>>(
      ctx, wpT, b_proj, outp);
}